// Round 5
// baseline (90.942 us; speedup 1.0000x reference)
//
#include <hip/hip_runtime.h>

// Karplus-Strong waveguide, decoupled + triple lag-doubled.
//   base (validated r1-r3):  S = D + A S,  A = g * Z^{2L} * e,  e = c⊛d (4 taps), g = gb*gn
//   expand n=0..7:           S[t] = D4[t] + g^8 * (e^{⊛8} ⊛ S)[t-16L]   (25 taps, lag P=16L)
//   D4 = Σ_{n=0..7} g^n e^{⊛n} ⊛ D(· - n*2L)     (grid-parallel prep)
//   out = S_l + S_r                               (grid-parallel add)
// seq kernel: 25 phases of P=3840 samples, distance-2 register prefetch via
// unroll-2 (no copy-induced vmcnt stalls), S stored in-place over D4, raw
// s_barrier with lgkm-only drain.

#define PREP_BLK 1024
#define SPAN_MAX 4640     // PREP_BLK + 7*(2*Lmax) + 21, Lmax=256
#define SEQ_BLK  512

template<int NA, int NB>
static __device__ __forceinline__ void convT(const float* a, const float* b, float* c) {
#pragma unroll
    for (int i = 0; i < NA + NB - 1; ++i) c[i] = 0.f;
#pragma unroll
    for (int i = 0; i < NA; ++i)
#pragma unroll
        for (int j = 0; j < NB; ++j) c[i + j] += a[i] * b[j];
}

struct Base {
    int L, nUp, nDown;
    float gb, gn, g;
    float c0, c1, c2, d0, d1;
    float e[4];
};

static __device__ __forceinline__ Base mkbase(const int* Lp, const float* pk,
        const float* gnp, const float* gbp, const float* bbp, const float* dap) {
    Base b;
    b.L = Lp[0];
    b.gn = gnp[0]; b.gb = gbp[0];
    const float bb = bbp[0], da = dap[0];
    b.nUp   = (int)rintf((float)b.L * pk[0]);   // round-half-even == jnp.round
    b.nDown = b.L - b.nUp;
    b.c0 = da * (1.f - bb);
    b.c1 = da * bb + (1.f - da) * (1.f - bb);
    b.c2 = (1.f - da) * bb;
    b.d0 = da; b.d1 = 1.f - da;
    b.e[0] = b.c0*b.d0;
    b.e[1] = b.c0*b.d1 + b.c1*b.d0;
    b.e[2] = b.c1*b.d1 + b.c2*b.d0;
    b.e[3] = b.c2*b.d1;
    b.g = b.gb * b.gn;
    return b;
}

// ---------------- prep: D4_l, D4_r (fully parallel over t) ----------------
__global__ __launch_bounds__(PREP_BLK, 1)
void prep_kernel(const int* Lp, const float* pk, const float* __restrict__ exc,
                 const float* gnp, const float* gbp, const float* bbp, const float* dap,
                 float* __restrict__ D4l, float* __restrict__ D4r, int T) {
    __shared__ float Dls[SPAN_MAX];
    __shared__ float Drs[SPAN_MAX];

    const Base B = mkbase(Lp, pk, gnp, gbp, bbp, dap);
    float p2[7], p3[10], p4[13], p5[16], p6[19], p7[22];
    convT<4,4>(B.e, B.e, p2);
    convT<7,4>(p2, B.e, p3);
    convT<7,7>(p2, p2, p4);
    convT<13,4>(p4, B.e, p5);
    convT<13,7>(p4, p2, p6);
    convT<13,10>(p4, p3, p7);
    const float g = B.g, g2 = g*g, g3 = g2*g, g4 = g2*g2, g5 = g4*g, g6 = g4*g2, g7 = g4*g3;

    const int P0   = 2 * B.L;
    const int H    = 7 * P0 + 21;           // deepest tap back-offset
    const int span = PREP_BLK + H;
    const int t0   = blockIdx.x * PREP_BLK;
    const int base = t0 - H;

    const int mx = (B.nUp > B.nDown) ? B.nUp : B.nDown;
    const bool safe = (base - B.L - mx - 2) >= 0;

    for (int j = threadIdx.x; j < span; j += PREP_BLK) {
        const int s = base + j;
        float dl, dr;
        if (safe) {
            dl = 0.5f * exc[s - B.nDown]
               + (0.5f * B.gb) * (B.c0 * exc[s - B.L     - B.nUp]
                                + B.c1 * exc[s - B.L - 1 - B.nUp]
                                + B.c2 * exc[s - B.L - 2 - B.nUp]);
            dr = 0.5f * exc[s - B.nUp]
               + (0.5f * B.gn) * (B.d0 * exc[s - B.L     - B.nDown]
                                + B.d1 * exc[s - B.L - 1 - B.nDown]);
        } else {
            auto ex = [&](int i) -> float { return (i >= 0) ? exc[i] : 0.f; };
            if (s < 0) { dl = 0.f; dr = 0.f; }
            else {
                dl = 0.5f * ex(s - B.nDown)
                   + (0.5f * B.gb) * (B.c0 * ex(s - B.L     - B.nUp)
                                    + B.c1 * ex(s - B.L - 1 - B.nUp)
                                    + B.c2 * ex(s - B.L - 2 - B.nUp));
                dr = 0.5f * ex(s - B.nUp)
                   + (0.5f * B.gn) * (B.d0 * ex(s - B.L     - B.nDown)
                                    + B.d1 * ex(s - B.L - 1 - B.nDown));
            }
        }
        Dls[j] = dl; Drs[j] = dr;
    }
    __syncthreads();

    const int t = t0 + threadIdx.x;
    if (t < T) {
        const int p = H + threadIdx.x;
        float al = Dls[p], ar = Drs[p];
#pragma unroll
        for (int k = 0; k < 4;  ++k) { const int j = p -     P0 - k; const float w = g  * B.e[k]; al += w*Dls[j]; ar += w*Drs[j]; }
#pragma unroll
        for (int k = 0; k < 7;  ++k) { const int j = p - 2 * P0 - k; const float w = g2 * p2[k];  al += w*Dls[j]; ar += w*Drs[j]; }
#pragma unroll
        for (int k = 0; k < 10; ++k) { const int j = p - 3 * P0 - k; const float w = g3 * p3[k];  al += w*Dls[j]; ar += w*Drs[j]; }
#pragma unroll
        for (int k = 0; k < 13; ++k) { const int j = p - 4 * P0 - k; const float w = g4 * p4[k];  al += w*Dls[j]; ar += w*Drs[j]; }
#pragma unroll
        for (int k = 0; k < 16; ++k) { const int j = p - 5 * P0 - k; const float w = g5 * p5[k];  al += w*Dls[j]; ar += w*Drs[j]; }
#pragma unroll
        for (int k = 0; k < 19; ++k) { const int j = p - 6 * P0 - k; const float w = g6 * p6[k];  al += w*Dls[j]; ar += w*Drs[j]; }
#pragma unroll
        for (int k = 0; k < 22; ++k) { const int j = p - 7 * P0 - k; const float w = g7 * p7[k];  al += w*Dls[j]; ar += w*Drs[j]; }
        D4l[t] = al; D4r[t] = ar;
    }
}

// ---------------- sequential: 25 phases of P=16L samples ----------------
// 512 threads: tid<256 -> S_l, else S_r; lane lam = tid&255, active lam < NA=L.
// Each thread owns 16 consecutive samples/chunk. Prev chunk in LDS planes
// pl[parity][arr][m][lane] (lane-stride 1 float4). 25-tap window = 24 floats
// from lanes lam-1 (16) and lam-2 (8) + own 16 regs. Lanes 0/1 read chunk
// q-2's 24-float tail from a 4-slot 'pre' ring (write slot q&3, read (q+2)&3).
__global__ __launch_bounds__(SEQ_BLK, 1)
void seq_kernel(const int* Lp, const float* pk, const float* gnp, const float* gbp,
                const float* bbp, const float* dap,
                float* __restrict__ Slw, float* __restrict__ Srw, int T) {
    __shared__ float4 pl[2][2][4][256];   // 64 KiB
    __shared__ float4 pre[4][2][6];

    const Base B = mkbase(Lp, pk, gnp, gbp, bbp, dap);
    float p2[7], p4[13], f[25];
    convT<4,4>(B.e, B.e, p2);
    convT<7,7>(p2, p2, p4);
    convT<13,13>(p4, p4, f);              // e^{*8}
    const float g2 = B.g * B.g, g4 = g2 * g2, G = g4 * g4;

    const int L = B.L, P = 16 * L, NA = L;
    const int tid = threadIdx.x, arr = tid >> 8, lam = tid & 255;
    const bool act = lam < NA;
    float* __restrict__ DD = arr ? Srw : Slw;   // D4 in, S out (in-place)

    {   float4* z = &pl[0][0][0][0];
        for (int i = tid; i < 2*2*4*256; i += SEQ_BLK) z[i] = float4{0,0,0,0};
        if (tid < 48) (&pre[0][0][0])[tid] = float4{0,0,0,0};
    }
    __syncthreads();

    const int nphase = (T + P - 1) / P;   // 25 for T=96000, L=240

    auto load16 = [&](int t, float4& a, float4& b, float4& c, float4& d) {
        if (t + 16 <= T) {
            a = *(const float4*)(DD + t);      b = *(const float4*)(DD + t + 4);
            c = *(const float4*)(DD + t + 8); d = *(const float4*)(DD + t + 12);
        } else {
            float tmp[16];
#pragma unroll
            for (int s = 0; s < 16; ++s) tmp[s] = (t + s < T) ? DD[t + s] : 0.f;
            a = float4{tmp[0],tmp[1],tmp[2],tmp[3]};   b = float4{tmp[4],tmp[5],tmp[6],tmp[7]};
            c = float4{tmp[8],tmp[9],tmp[10],tmp[11]}; d = float4{tmp[12],tmp[13],tmp[14],tmp[15]};
        }
    };

    float4 dE[4] = {{0,0,0,0},{0,0,0,0},{0,0,0,0},{0,0,0,0}};
    float4 dO[4] = {{0,0,0,0},{0,0,0,0},{0,0,0,0},{0,0,0,0}};
    if (act)               load16(lam << 4,     dE[0], dE[1], dE[2], dE[3]);
    if (act && nphase > 1) load16(P + (lam<<4), dO[0], dO[1], dO[2], dO[3]);

    float4 pS0{0,0,0,0}, pS1{0,0,0,0}, pS2{0,0,0,0}, pS3{0,0,0,0};

    auto do_phase = [&](int q, float4 (&dv)[4]) {
        const int par = q & 1, pp = par ^ 1, rs = (q + 2) & 3, wsl = q & 3;

        float4 B2{0,0,0,0}, B3{0,0,0,0}, A0{0,0,0,0}, A1{0,0,0,0}, A2{0,0,0,0}, A3{0,0,0,0};
        if (act) {
            if (lam >= 2) {
                B2 = pl[pp][arr][2][lam-2]; B3 = pl[pp][arr][3][lam-2];
                A0 = pl[pp][arr][0][lam-1]; A1 = pl[pp][arr][1][lam-1];
                A2 = pl[pp][arr][2][lam-1]; A3 = pl[pp][arr][3][lam-1];
            } else if (lam == 1) {
                B2 = pre[rs][arr][4]; B3 = pre[rs][arr][5];
                A0 = pl[pp][arr][0][0]; A1 = pl[pp][arr][1][0];
                A2 = pl[pp][arr][2][0]; A3 = pl[pp][arr][3][0];
            } else {
                B2 = pre[rs][arr][0]; B3 = pre[rs][arr][1];
                A0 = pre[rs][arr][2]; A1 = pre[rs][arr][3];
                A2 = pre[rs][arr][4]; A3 = pre[rs][arr][5];
            }
        }

        float S[16];
        if (act) {
            float cw[40];
            cw[0]=B2.x; cw[1]=B2.y; cw[2]=B2.z; cw[3]=B2.w;
            cw[4]=B3.x; cw[5]=B3.y; cw[6]=B3.z; cw[7]=B3.w;
            cw[8]=A0.x; cw[9]=A0.y; cw[10]=A0.z; cw[11]=A0.w;
            cw[12]=A1.x; cw[13]=A1.y; cw[14]=A1.z; cw[15]=A1.w;
            cw[16]=A2.x; cw[17]=A2.y; cw[18]=A2.z; cw[19]=A2.w;
            cw[20]=A3.x; cw[21]=A3.y; cw[22]=A3.z; cw[23]=A3.w;
            cw[24]=pS0.x; cw[25]=pS0.y; cw[26]=pS0.z; cw[27]=pS0.w;
            cw[28]=pS1.x; cw[29]=pS1.y; cw[30]=pS1.z; cw[31]=pS1.w;
            cw[32]=pS2.x; cw[33]=pS2.y; cw[34]=pS2.z; cw[35]=pS2.w;
            cw[36]=pS3.x; cw[37]=pS3.y; cw[38]=pS3.z; cw[39]=pS3.w;
            const float dvf[16] = {dv[0].x,dv[0].y,dv[0].z,dv[0].w,
                                   dv[1].x,dv[1].y,dv[1].z,dv[1].w,
                                   dv[2].x,dv[2].y,dv[2].z,dv[2].w,
                                   dv[3].x,dv[3].y,dv[3].z,dv[3].w};
#pragma unroll
            for (int s = 0; s < 16; ++s) {
                float a0 = 0.f, a1 = 0.f;
#pragma unroll
                for (int k = 0; k < 25; k += 2) a0 += f[k] * cw[24 + s - k];
#pragma unroll
                for (int k = 1; k < 25; k += 2) a1 += f[k] * cw[24 + s - k];
                S[s] = dvf[s] + G * (a0 + a1);
            }
        }

        // prefetch chunk q+2 into dv (dv consumed above; 2-phase slack, no copies)
        if (act && (q + 2) < nphase) load16((q + 2) * P + (lam << 4), dv[0], dv[1], dv[2], dv[3]);

        if (act) {
            pS0 = float4{S[0],S[1],S[2],S[3]};   pS1 = float4{S[4],S[5],S[6],S[7]};
            pS2 = float4{S[8],S[9],S[10],S[11]}; pS3 = float4{S[12],S[13],S[14],S[15]};
            pl[par][arr][0][lam] = pS0; pl[par][arr][1][lam] = pS1;
            pl[par][arr][2][lam] = pS2; pl[par][arr][3][lam] = pS3;
            if (lam == NA - 2) { pre[wsl][arr][0] = pS2; pre[wsl][arr][1] = pS3; }
            if (lam == NA - 1) { pre[wsl][arr][2] = pS0; pre[wsl][arr][3] = pS1;
                                 pre[wsl][arr][4] = pS2; pre[wsl][arr][5] = pS3; }
            // fire-and-forget store of S chunk q over dead D4 chunk q
            const int tg = q * P + (lam << 4);
            if (tg + 16 <= T) {
                *(float4*)(DD + tg)      = pS0; *(float4*)(DD + tg + 4)  = pS1;
                *(float4*)(DD + tg + 8)  = pS2; *(float4*)(DD + tg + 12) = pS3;
            } else {
#pragma unroll
                for (int s = 0; s < 16; ++s) if (tg + s < T) DD[tg + s] = S[s];
            }
        }

        asm volatile("s_waitcnt lgkmcnt(0)" ::: "memory");
        __builtin_amdgcn_sched_barrier(0);
        __builtin_amdgcn_s_barrier();
        __builtin_amdgcn_sched_barrier(0);
    };

    int q = 0;
    for (; q + 1 < nphase; q += 2) { do_phase(q, dE); do_phase(q + 1, dO); }
    if (q < nphase) do_phase(q, dE);
}

// ---------------- add: out = S_l + S_r (fully parallel) ----------------
__global__ void add_kernel(const float* __restrict__ a, const float* __restrict__ b,
                           float* __restrict__ o, int T) {
    const int i = (blockIdx.x * blockDim.x + threadIdx.x) * 4;
    if (i + 4 <= T) {
        const float4 x = *(const float4*)(a + i);
        const float4 y = *(const float4*)(b + i);
        *(float4*)(o + i) = float4{x.x + y.x, x.y + y.y, x.z + y.z, x.w + y.w};
    } else if (i < T) {
        for (int s = i; s < T; ++s) o[s] = a[s] + b[s];
    }
}

extern "C" void kernel_launch(void* const* d_in, const int* in_sizes, int n_in,
                              void* d_out, int out_size, void* d_ws, size_t ws_size,
                              hipStream_t stream) {
    const int*   Lp  = (const int*)  d_in[0];
    const float* pk  = (const float*)d_in[1];
    const float* exc = (const float*)d_in[2];
    const float* gn  = (const float*)d_in[3];
    const float* gb  = (const float*)d_in[4];
    const float* bb  = (const float*)d_in[5];
    const float* da  = (const float*)d_in[6];
    float* out = (float*)d_out;
    float* D4l = (float*)d_ws;
    float* D4r = D4l + out_size;
    const int T = out_size;

    prep_kernel<<<(T + PREP_BLK - 1) / PREP_BLK, PREP_BLK, 0, stream>>>(
        Lp, pk, exc, gn, gb, bb, da, D4l, D4r, T);
    seq_kernel<<<1, SEQ_BLK, 0, stream>>>(Lp, pk, gn, gb, bb, da, D4l, D4r, T);
    add_kernel<<<(T / 4 + 255) / 256, 256, 0, stream>>>(D4l, D4r, out, T);
}

// Round 6
// 55.797 us; speedup vs baseline: 1.6299x; 1.6299x over previous
//
#include <hip/hip_runtime.h>

// Karplus-Strong waveguide, decoupled + triple lag-doubled.
//   base (validated r1-r3):  S = D + A S,  A = g * Z^{2L} * e,  e = c⊛d (4 taps), g = gb*gn
//   expand n=0..7:           S[t] = D4[t] + g^8 * (e^{⊛8} ⊛ S)[t-16L]   (25 taps, lag P=16L)
//   D4 = Σ_{n=0..7} g^n e^{⊛n} ⊛ D(· - n*2L)     (grid-parallel prep)
//   out = S_l + S_r                               (grid-parallel add)
// Round 6: S_l and S_r are INDEPENDENT -> 2 workgroups (one per array, on
// different CUs), 256 threads each (1 wave/SIMD). Halves per-CU FIR issue.

#define PREP_BLK 1024
#define SPAN_MAX 4640     // PREP_BLK + 7*(2*Lmax) + 21, Lmax=256
#define SEQ_BLK  256

template<int NA, int NB>
static __device__ __forceinline__ void convT(const float* a, const float* b, float* c) {
#pragma unroll
    for (int i = 0; i < NA + NB - 1; ++i) c[i] = 0.f;
#pragma unroll
    for (int i = 0; i < NA; ++i)
#pragma unroll
        for (int j = 0; j < NB; ++j) c[i + j] += a[i] * b[j];
}

struct Base {
    int L, nUp, nDown;
    float gb, gn, g;
    float c0, c1, c2, d0, d1;
    float e[4];
};

static __device__ __forceinline__ Base mkbase(const int* Lp, const float* pk,
        const float* gnp, const float* gbp, const float* bbp, const float* dap) {
    Base b;
    b.L = Lp[0];
    b.gn = gnp[0]; b.gb = gbp[0];
    const float bb = bbp[0], da = dap[0];
    b.nUp   = (int)rintf((float)b.L * pk[0]);   // round-half-even == jnp.round
    b.nDown = b.L - b.nUp;
    b.c0 = da * (1.f - bb);
    b.c1 = da * bb + (1.f - da) * (1.f - bb);
    b.c2 = (1.f - da) * bb;
    b.d0 = da; b.d1 = 1.f - da;
    b.e[0] = b.c0*b.d0;
    b.e[1] = b.c0*b.d1 + b.c1*b.d0;
    b.e[2] = b.c1*b.d1 + b.c2*b.d0;
    b.e[3] = b.c2*b.d1;
    b.g = b.gb * b.gn;
    return b;
}

// ---------------- prep: D4_l, D4_r (fully parallel over t) ----------------
__global__ __launch_bounds__(PREP_BLK, 1)
void prep_kernel(const int* Lp, const float* pk, const float* __restrict__ exc,
                 const float* gnp, const float* gbp, const float* bbp, const float* dap,
                 float* __restrict__ D4l, float* __restrict__ D4r, int T) {
    __shared__ float Dls[SPAN_MAX];
    __shared__ float Drs[SPAN_MAX];

    const Base B = mkbase(Lp, pk, gnp, gbp, bbp, dap);
    float p2[7], p3[10], p4[13], p5[16], p6[19], p7[22];
    convT<4,4>(B.e, B.e, p2);
    convT<7,4>(p2, B.e, p3);
    convT<7,7>(p2, p2, p4);
    convT<13,4>(p4, B.e, p5);
    convT<13,7>(p4, p2, p6);
    convT<13,10>(p4, p3, p7);
    const float g = B.g, g2 = g*g, g3 = g2*g, g4 = g2*g2, g5 = g4*g, g6 = g4*g2, g7 = g4*g3;

    const int P0   = 2 * B.L;
    const int H    = 7 * P0 + 21;           // deepest tap back-offset
    const int span = PREP_BLK + H;
    const int t0   = blockIdx.x * PREP_BLK;
    const int base = t0 - H;

    const int mx = (B.nUp > B.nDown) ? B.nUp : B.nDown;
    const bool safe = (base - B.L - mx - 2) >= 0;

    for (int j = threadIdx.x; j < span; j += PREP_BLK) {
        const int s = base + j;
        float dl, dr;
        if (safe) {
            dl = 0.5f * exc[s - B.nDown]
               + (0.5f * B.gb) * (B.c0 * exc[s - B.L     - B.nUp]
                                + B.c1 * exc[s - B.L - 1 - B.nUp]
                                + B.c2 * exc[s - B.L - 2 - B.nUp]);
            dr = 0.5f * exc[s - B.nUp]
               + (0.5f * B.gn) * (B.d0 * exc[s - B.L     - B.nDown]
                                + B.d1 * exc[s - B.L - 1 - B.nDown]);
        } else {
            auto ex = [&](int i) -> float { return (i >= 0) ? exc[i] : 0.f; };
            if (s < 0) { dl = 0.f; dr = 0.f; }
            else {
                dl = 0.5f * ex(s - B.nDown)
                   + (0.5f * B.gb) * (B.c0 * ex(s - B.L     - B.nUp)
                                    + B.c1 * ex(s - B.L - 1 - B.nUp)
                                    + B.c2 * ex(s - B.L - 2 - B.nUp));
                dr = 0.5f * ex(s - B.nUp)
                   + (0.5f * B.gn) * (B.d0 * ex(s - B.L     - B.nDown)
                                    + B.d1 * ex(s - B.L - 1 - B.nDown));
            }
        }
        Dls[j] = dl; Drs[j] = dr;
    }
    __syncthreads();

    const int t = t0 + threadIdx.x;
    if (t < T) {
        const int p = H + threadIdx.x;
        float al = Dls[p], ar = Drs[p];
#pragma unroll
        for (int k = 0; k < 4;  ++k) { const int j = p -     P0 - k; const float w = g  * B.e[k]; al += w*Dls[j]; ar += w*Drs[j]; }
#pragma unroll
        for (int k = 0; k < 7;  ++k) { const int j = p - 2 * P0 - k; const float w = g2 * p2[k];  al += w*Dls[j]; ar += w*Drs[j]; }
#pragma unroll
        for (int k = 0; k < 10; ++k) { const int j = p - 3 * P0 - k; const float w = g3 * p3[k];  al += w*Dls[j]; ar += w*Drs[j]; }
#pragma unroll
        for (int k = 0; k < 13; ++k) { const int j = p - 4 * P0 - k; const float w = g4 * p4[k];  al += w*Dls[j]; ar += w*Drs[j]; }
#pragma unroll
        for (int k = 0; k < 16; ++k) { const int j = p - 5 * P0 - k; const float w = g5 * p5[k];  al += w*Dls[j]; ar += w*Drs[j]; }
#pragma unroll
        for (int k = 0; k < 19; ++k) { const int j = p - 6 * P0 - k; const float w = g6 * p6[k];  al += w*Dls[j]; ar += w*Drs[j]; }
#pragma unroll
        for (int k = 0; k < 22; ++k) { const int j = p - 7 * P0 - k; const float w = g7 * p7[k];  al += w*Dls[j]; ar += w*Drs[j]; }
        D4l[t] = al; D4r[t] = ar;
    }
}

// ---------------- sequential: 2 blocks (one array each), 25 phases ----------------
// Block arr handles S_arr. 256 threads, active lam < NA = L, 16 samples/thread.
// Prev chunk in LDS planes pl[parity][m][lane] (lane-stride 1 float4).
// 25-tap window = 24 floats from lanes lam-1 (16) + lam-2 (8) + own 16 regs.
// Lanes 0/1 read chunk q-2's 24-float tail from a 4-slot 'pre' ring
// (write slot q&3, read (q+2)&3 -> written at phase q-2, never same-phase).
__global__ __launch_bounds__(SEQ_BLK, 1)
void seq_kernel(const int* Lp, const float* pk, const float* gnp, const float* gbp,
                const float* bbp, const float* dap,
                float* __restrict__ Slw, float* __restrict__ Srw, int T) {
    __shared__ float4 pl[2][4][256];   // 32 KiB
    __shared__ float4 pre[4][6];

    const Base B = mkbase(Lp, pk, gnp, gbp, bbp, dap);
    float p2[7], p4[13], f[25];
    convT<4,4>(B.e, B.e, p2);
    convT<7,7>(p2, p2, p4);
    convT<13,13>(p4, p4, f);              // e^{*8}
    const float g2 = B.g * B.g, g4 = g2 * g2, G = g4 * g4;

    const int L = B.L, P = 16 * L, NA = L;     // NA <= 256 for L <= 256
    const int lam = threadIdx.x;
    const bool act = lam < NA;
    float* __restrict__ DD = blockIdx.x ? Srw : Slw;   // D4 in, S out (in-place)

    {   float4* z = &pl[0][0][0];
        for (int i = lam; i < 2*4*256; i += SEQ_BLK) z[i] = float4{0,0,0,0};
        if (lam < 24) (&pre[0][0])[lam] = float4{0,0,0,0};
    }
    __syncthreads();

    const int nphase = (T + P - 1) / P;   // 25 for T=96000, L=240

    auto load16 = [&](int t, float4& a, float4& b, float4& c, float4& d) {
        if (t + 16 <= T) {
            a = *(const float4*)(DD + t);      b = *(const float4*)(DD + t + 4);
            c = *(const float4*)(DD + t + 8); d = *(const float4*)(DD + t + 12);
        } else {
            float tmp[16];
#pragma unroll
            for (int s = 0; s < 16; ++s) tmp[s] = (t + s < T) ? DD[t + s] : 0.f;
            a = float4{tmp[0],tmp[1],tmp[2],tmp[3]};   b = float4{tmp[4],tmp[5],tmp[6],tmp[7]};
            c = float4{tmp[8],tmp[9],tmp[10],tmp[11]}; d = float4{tmp[12],tmp[13],tmp[14],tmp[15]};
        }
    };

    float4 dE[4] = {{0,0,0,0},{0,0,0,0},{0,0,0,0},{0,0,0,0}};
    float4 dO[4] = {{0,0,0,0},{0,0,0,0},{0,0,0,0},{0,0,0,0}};
    if (act)               load16(lam << 4,     dE[0], dE[1], dE[2], dE[3]);
    if (act && nphase > 1) load16(P + (lam<<4), dO[0], dO[1], dO[2], dO[3]);

    float4 pS0{0,0,0,0}, pS1{0,0,0,0}, pS2{0,0,0,0}, pS3{0,0,0,0};

    auto do_phase = [&](int q, float4 (&dv)[4]) {
        const int par = q & 1, pp = par ^ 1, rs = (q + 2) & 3, wsl = q & 3;

        float4 B2{0,0,0,0}, B3{0,0,0,0}, A0{0,0,0,0}, A1{0,0,0,0}, A2{0,0,0,0}, A3{0,0,0,0};
        if (act) {
            if (lam >= 2) {
                B2 = pl[pp][2][lam-2]; B3 = pl[pp][3][lam-2];
                A0 = pl[pp][0][lam-1]; A1 = pl[pp][1][lam-1];
                A2 = pl[pp][2][lam-1]; A3 = pl[pp][3][lam-1];
            } else if (lam == 1) {
                B2 = pre[rs][4]; B3 = pre[rs][5];
                A0 = pl[pp][0][0]; A1 = pl[pp][1][0];
                A2 = pl[pp][2][0]; A3 = pl[pp][3][0];
            } else {
                B2 = pre[rs][0]; B3 = pre[rs][1];
                A0 = pre[rs][2]; A1 = pre[rs][3];
                A2 = pre[rs][4]; A3 = pre[rs][5];
            }
        }

        float S[16];
        if (act) {
            float cw[40];
            cw[0]=B2.x; cw[1]=B2.y; cw[2]=B2.z; cw[3]=B2.w;
            cw[4]=B3.x; cw[5]=B3.y; cw[6]=B3.z; cw[7]=B3.w;
            cw[8]=A0.x; cw[9]=A0.y; cw[10]=A0.z; cw[11]=A0.w;
            cw[12]=A1.x; cw[13]=A1.y; cw[14]=A1.z; cw[15]=A1.w;
            cw[16]=A2.x; cw[17]=A2.y; cw[18]=A2.z; cw[19]=A2.w;
            cw[20]=A3.x; cw[21]=A3.y; cw[22]=A3.z; cw[23]=A3.w;
            cw[24]=pS0.x; cw[25]=pS0.y; cw[26]=pS0.z; cw[27]=pS0.w;
            cw[28]=pS1.x; cw[29]=pS1.y; cw[30]=pS1.z; cw[31]=pS1.w;
            cw[32]=pS2.x; cw[33]=pS2.y; cw[34]=pS2.z; cw[35]=pS2.w;
            cw[36]=pS3.x; cw[37]=pS3.y; cw[38]=pS3.z; cw[39]=pS3.w;
            const float dvf[16] = {dv[0].x,dv[0].y,dv[0].z,dv[0].w,
                                   dv[1].x,dv[1].y,dv[1].z,dv[1].w,
                                   dv[2].x,dv[2].y,dv[2].z,dv[2].w,
                                   dv[3].x,dv[3].y,dv[3].z,dv[3].w};
#pragma unroll
            for (int s = 0; s < 16; ++s) {
                float a0 = 0.f, a1 = 0.f;
#pragma unroll
                for (int k = 0; k < 25; k += 2) a0 += f[k] * cw[24 + s - k];
#pragma unroll
                for (int k = 1; k < 25; k += 2) a1 += f[k] * cw[24 + s - k];
                S[s] = dvf[s] + G * (a0 + a1);
            }
        }

        // prefetch chunk q+2 into dv (dv consumed above; 2-phase slack, no copies)
        if (act && (q + 2) < nphase) load16((q + 2) * P + (lam << 4), dv[0], dv[1], dv[2], dv[3]);

        if (act) {
            pS0 = float4{S[0],S[1],S[2],S[3]};   pS1 = float4{S[4],S[5],S[6],S[7]};
            pS2 = float4{S[8],S[9],S[10],S[11]}; pS3 = float4{S[12],S[13],S[14],S[15]};
            pl[par][0][lam] = pS0; pl[par][1][lam] = pS1;
            pl[par][2][lam] = pS2; pl[par][3][lam] = pS3;
            if (lam == NA - 2) { pre[wsl][0] = pS2; pre[wsl][1] = pS3; }
            if (lam == NA - 1) { pre[wsl][2] = pS0; pre[wsl][3] = pS1;
                                 pre[wsl][4] = pS2; pre[wsl][5] = pS3; }
            // fire-and-forget store of S chunk q over dead D4 chunk q
            const int tg = q * P + (lam << 4);
            if (tg + 16 <= T) {
                *(float4*)(DD + tg)      = pS0; *(float4*)(DD + tg + 4)  = pS1;
                *(float4*)(DD + tg + 8)  = pS2; *(float4*)(DD + tg + 12) = pS3;
            } else {
#pragma unroll
                for (int s = 0; s < 16; ++s) if (tg + s < T) DD[tg + s] = S[s];
            }
        }

        asm volatile("s_waitcnt lgkmcnt(0)" ::: "memory");
        __builtin_amdgcn_sched_barrier(0);
        __builtin_amdgcn_s_barrier();
        __builtin_amdgcn_sched_barrier(0);
    };

    int q = 0;
    for (; q + 1 < nphase; q += 2) { do_phase(q, dE); do_phase(q + 1, dO); }
    if (q < nphase) do_phase(q, dE);
}

// ---------------- add: out = S_l + S_r (fully parallel) ----------------
__global__ void add_kernel(const float* __restrict__ a, const float* __restrict__ b,
                           float* __restrict__ o, int T) {
    const int i = (blockIdx.x * blockDim.x + threadIdx.x) * 4;
    if (i + 4 <= T) {
        const float4 x = *(const float4*)(a + i);
        const float4 y = *(const float4*)(b + i);
        *(float4*)(o + i) = float4{x.x + y.x, x.y + y.y, x.z + y.z, x.w + y.w};
    } else if (i < T) {
        for (int s = i; s < T; ++s) o[s] = a[s] + b[s];
    }
}

extern "C" void kernel_launch(void* const* d_in, const int* in_sizes, int n_in,
                              void* d_out, int out_size, void* d_ws, size_t ws_size,
                              hipStream_t stream) {
    const int*   Lp  = (const int*)  d_in[0];
    const float* pk  = (const float*)d_in[1];
    const float* exc = (const float*)d_in[2];
    const float* gn  = (const float*)d_in[3];
    const float* gb  = (const float*)d_in[4];
    const float* bb  = (const float*)d_in[5];
    const float* da  = (const float*)d_in[6];
    float* out = (float*)d_out;
    float* D4l = (float*)d_ws;
    float* D4r = D4l + out_size;
    const int T = out_size;

    prep_kernel<<<(T + PREP_BLK - 1) / PREP_BLK, PREP_BLK, 0, stream>>>(
        Lp, pk, exc, gn, gb, bb, da, D4l, D4r, T);
    seq_kernel<<<2, SEQ_BLK, 0, stream>>>(Lp, pk, gn, gb, bb, da, D4l, D4r, T);
    add_kernel<<<(T / 4 + 255) / 256, 256, 0, stream>>>(D4l, D4r, out, T);
}